// Round 7
// baseline (410.022 us; speedup 1.0000x reference)
//
#include <hip/hip_runtime.h>
#include <hip/hip_bf16.h>

#define NPTS 150
#define KP   168          // padded K for MFMA; 5 K-steps of 32 cover 0..159
#define NPAR 193
#define OSTR 388

// bf16 transposed activation buffers, element offsets into sT
#define H1T  0            // [11][168]  rows 0..9 = h1^T, row 10 = ones (db2)
#define H2T  1848         // [11][168]  rows 0..9 = h2^T, row 10 = ones (db3)
#define XT   3696         // [5][168]   rows 0..3 = x^T,  row 4  = ones (db1)
#define DZ2T 4536         // [10][168]
#define DZ1T 6216         // [10][168]
#define DLT  7896         // [3][168]
#define TTOT 8400

typedef __attribute__((ext_vector_type(8))) short short8;
typedef __attribute__((ext_vector_type(4))) float f32x4;

__constant__ float LRS[6] = {0.001f, 0.01f, 0.05f, 0.1f, 0.5f, 1.0f};

// Round-7: EXACT r1 per-MLP body (177-183us proven) inside a rep-loop of 2;
// grid halves to 16384. Theory: r1<->r3 showed A-time is insensitive to VALU
// instruction count; occupancy (10.1 waves/CU) sits BELOW the static cap (16)
// -> suspect is block service rate (~179 blocks/us). r2/r5 "more work per
// block" both changed the body (prefetch rewrite / 384-thr geometry) and
// regressed; this is the clean test: body untouched, blocks halved.
// Safety: B3 (last barrier of rep k) orders all MFMA reads of sT before
// rep k+1's zero-fill; sP rewrites also come after B3. Uniform m per block
// -> the m>=Bn break is exec-uniform.
__global__ __launch_bounds__(192)
__attribute__((amdgpu_waves_per_eu(2, 4)))
void mlp_kernelA(
    const float* __restrict__ W1, const float* __restrict__ b1,
    const float* __restrict__ W2, const float* __restrict__ b2,
    const float* __restrict__ W3, const float* __restrict__ b3,
    const float* __restrict__ G1, const float* __restrict__ G2,
    const float* __restrict__ G3, const float* __restrict__ G4,
    const float* __restrict__ G5, const float* __restrict__ G6,
    const float* __restrict__ dx, const float* __restrict__ fv,
    const int* __restrict__ dy, const int* __restrict__ stepsz,
    float* __restrict__ out, float* __restrict__ slots,
    int Bn, int storeMode)
{
    const int t    = threadIdx.x;
    const int lane = t & 63;
    const int w    = t >> 6;

    __shared__ alignas(16) __hip_bfloat16 sT[TTOT];
    __shared__ alignas(16) float sP[200];
    __shared__ float red[8];

    for (int rep = 0; rep < 2; rep++) {
        const int m = blockIdx.x * 2 + rep;
        if (m >= Bn) break;                      // uniform across block

        const float lr = LRS[stepsz[m]];

        // ---- SGD update: thread t owns param index t (t=0 also does 192) ----
        float pv;
        if      (t < 40)  pv = W1[m*40 + t]        - lr * G1[m*40 + t];
        else if (t < 50)  pv = b1[m*10 + (t-40)]   - lr * G2[m*10 + (t-40)];
        else if (t < 150) pv = W2[m*100 + (t-50)]  - lr * G3[m*100 + (t-50)];
        else if (t < 160) pv = b2[m*10 + (t-150)]  - lr * G4[m*10 + (t-150)];
        else if (t < 190) pv = W3[m*30 + (t-160)]  - lr * G5[m*30 + (t-160)];
        else              pv = b3[m*3 + (t-190)]   - lr * G6[m*3 + (t-190)];
        sP[t] = pv;
        out[(size_t)m*OSTR + t] = fminf(fmaxf(pv, -10000.f), 10000.f);
        if (t == 0) {
            float p192 = b3[m*3 + 2] - lr * G6[m*3 + 2];
            sP[192] = p192;
            out[(size_t)m*OSTR + 192] = fminf(fmaxf(p192, -10000.f), 10000.f);
        }

        // ---- zero the whole bf16 T-buffer (pad cols MUST be finite zeros) ----
        {
            f32x4 z = {0.f, 0.f, 0.f, 0.f};
            f32x4* p = (f32x4*)sT;                 // 8400 bf16 = 1050 x 16B
            for (int i = t; i < 1050; i += 192) p[i] = z;
        }
        __syncthreads();   // B1

        // ---- ones rows (bias-grad columns) ----
        if (t < KP) {
            __hip_bfloat16 one = __float2bfloat16(1.0f);
            sT[H1T + 10*KP + t] = one;
            sT[H2T + 10*KP + t] = one;
            sT[XT  +  4*KP + t] = one;
        }
        // ---- x^T fill: x^T[f][n] = x[n][f] ----
        for (int i = t; i < 600; i += 192) {
            int n = i >> 2, f = i & 3;
            sT[XT + f*KP + n] = __float2bfloat16(dx[i]);
        }

        // ---- per-wave preload of wave-uniform params (broadcast LDS reads) ----
        float w2[10][10], bb2[10], w3[3][10], bb3[3], bb1[10];
        #pragma unroll
        for (int g = 0; g < 10; g++) {
            #pragma unroll
            for (int h = 0; h < 10; h++) w2[g][h] = sP[50 + g*10 + h];
            bb2[g] = sP[150 + g];
            bb1[g] = sP[40 + g];
        }
        #pragma unroll
        for (int o = 0; o < 3; o++) {
            #pragma unroll
            for (int g = 0; g < 10; g++) w3[o][g] = sP[160 + o*10 + g];
            bb3[o] = sP[190 + o];
        }
        const f32x4* sP4 = (const f32x4*)sP;   // W1 row j at sP4[j]

        // ============= fused forward + backward-dz: ONE point per thread =====
        float lossacc = 0.f, ssacc = 0.f;
        {
            const int  n   = t;
            const bool act = (n < NPTS);
            const int  nc  = act ? n : 0;

            f32x4 xv = ((const f32x4*)dx)[nc];
            int   yv = dy[nc];

            float h1v[10];
            #pragma unroll
            for (int j = 0; j < 10; j++) {
                f32x4 wv = sP4[j];
                float z = bb1[j] + xv.x*wv.x + xv.y*wv.y + xv.z*wv.z + xv.w*wv.w;
                h1v[j] = fmaxf(z, 0.f);
            }
            float h2v[10];
            #pragma unroll
            for (int g = 0; g < 10; g++) {
                float z = bb2[g];
                #pragma unroll
                for (int h = 0; h < 10; h++) z += h1v[h] * w2[g][h];
                h2v[g] = fmaxf(z, 0.f);
            }
            float lg[3];
            #pragma unroll
            for (int o = 0; o < 3; o++) {
                float z = bb3[o];
                #pragma unroll
                for (int g = 0; g < 10; g++) z += h2v[g] * w3[o][g];
                lg[o] = z;
            }
            float mx = fmaxf(lg[0], fmaxf(lg[1], lg[2]));
            float e0 = __expf(lg[0]-mx), e1 = __expf(lg[1]-mx), e2 = __expf(lg[2]-mx);
            float s   = e0 + e1 + e2;
            float inv = 1.f / s;
            float lse = mx + __logf(s);
            float ly  = (yv == 0) ? lg[0] : ((yv == 1) ? lg[1] : lg[2]);
            lossacc = act ? (lse - ly) : 0.f;

            float dl[3];
            dl[0] = (e0*inv - ((yv==0)?1.f:0.f)) * (1.f/150.f);
            dl[1] = (e1*inv - ((yv==1)?1.f:0.f)) * (1.f/150.f);
            dl[2] = (e2*inv - ((yv==2)?1.f:0.f)) * (1.f/150.f);

            float dz2v[10];
            #pragma unroll
            for (int g = 0; g < 10; g++) {
                float d = dl[0]*w3[0][g] + dl[1]*w3[1][g] + dl[2]*w3[2][g];
                dz2v[g] = (h2v[g] > 0.f) ? d : 0.f;
            }
            float dz1v[10];
            #pragma unroll
            for (int h = 0; h < 10; h++) {
                float d = 0.f;
                #pragma unroll
                for (int g = 0; g < 10; g++) d += dz2v[g] * w2[g][h];
                dz1v[h] = (h1v[h] > 0.f) ? d : 0.f;
            }

            if (act) {
                #pragma unroll
                for (int j = 0; j < 10; j++) sT[H1T  + j*KP + n] = __float2bfloat16(h1v[j]);
                #pragma unroll
                for (int g = 0; g < 10; g++) sT[H2T  + g*KP + n] = __float2bfloat16(h2v[g]);
                #pragma unroll
                for (int o = 0; o < 3;  o++) sT[DLT  + o*KP + n] = __float2bfloat16(dl[o]);
                #pragma unroll
                for (int g = 0; g < 10; g++) sT[DZ2T + g*KP + n] = __float2bfloat16(dz2v[g]);
                #pragma unroll
                for (int h = 0; h < 10; h++) sT[DZ1T + h*KP + n] = __float2bfloat16(dz1v[h]);
            }
        }
        __syncthreads();   // B2

        // ============= weight-grad GEMMs via MFMA: one tile per wave =========
        {
            const short* sTs = reinterpret_cast<const short*>(sT);
            const int mrow = lane & 15, q = lane >> 4;

            int abase, arows, bbase, bcols, woff, nW, boff;
            if      (w == 0) { abase=DZ2T; arows=10; bbase=H1T; bcols=11; woff=50;  nW=10; boff=150; }
            else if (w == 1) { abase=DZ1T; arows=10; bbase=XT;  bcols=5;  woff=0;   nW=4;  boff=40;  }
            else             { abase=DLT;  arows=3;  bbase=H2T; bcols=11; woff=160; nW=10; boff=190; }

            int ar = (mrow < arows) ? mrow : 0;
            int br = (mrow < bcols) ? mrow : 0;
            f32x4 acc = {0.f, 0.f, 0.f, 0.f};
            #pragma unroll
            for (int kk = 0; kk < 5; kk++) {
                int k0 = kk*32 + q*8;
                short8 a = *(const short8*)(sTs + abase + ar*KP + k0);
                short8 b = *(const short8*)(sTs + bbase + br*KP + k0);
                acc = __builtin_amdgcn_mfma_f32_16x16x32_bf16(a, b, acc, 0, 0, 0);
            }
            #pragma unroll
            for (int r = 0; r < 4; r++) {
                int row = q*4 + r;
                if (row < arows && mrow < bcols) {
                    float v = acc[r];
                    int off = (mrow < nW) ? (woff + row*nW + mrow) : (boff + row);
                    out[(size_t)m*OSTR + NPAR + off] = v;   // raw; BC scales
                    ssacc += v*v;
                }
            }
        }

        // ---- reductions: loss (across all 3 waves), sumsq (per-wave) ----
        #pragma unroll
        for (int off = 32; off > 0; off >>= 1) {
            lossacc += __shfl_down(lossacc, off, 64);
            ssacc   += __shfl_down(ssacc,   off, 64);
        }
        if (lane == 0) { red[w] = lossacc; red[4 + w] = ssacc; }
        __syncthreads();   // B3 — also orders sT/sP reuse for next rep
        if (t == 0) {
            float blockss = red[4] + red[5] + red[6];
            if (storeMode) slots[1 + m] = blockss;
            else           atomicAdd(&slots[1 + (m & 1023)], blockss);
            float loss = (red[0] + red[1] + red[2]) * (1.f/150.f);
            out[(size_t)m*OSTR + 386] = loss;
            float imp = fv[m] - loss;
            imp = fminf(fmaxf(imp, -10000.f), 10000.f);
            out[(size_t)m*OSTR + 387] = imp;
        }
    }
}

// Fused B+C (launch-count theory: non-A ~105us is invariant to B/C structure
// -> ~35us/launch fixed cost suspected; drop one launch). Every block
// redundantly reduces slots[1..count] (L2-resident, ~4us aggregate), derives
// coef locally, then scales its grid-stride share. No atomics, no memset
// needed in storeMode, no grid sync.
__global__ __launch_bounds__(256) void mlp_kernelBC(float* __restrict__ out,
                                                    const float* __restrict__ slots,
                                                    int count, int total)
{
    int t = threadIdx.x;
    float v = 0.f;
    for (int i = t; i < count; i += 256) v += slots[1 + i];
    #pragma unroll
    for (int off = 32; off > 0; off >>= 1) v += __shfl_down(v, off, 64);
    __shared__ float red[4];
    __shared__ float coefS;
    if ((t & 63) == 0) red[t >> 6] = v;
    __syncthreads();
    if (t == 0) {
        float tot = red[0] + red[1] + red[2] + red[3];
        coefS = fminf(1.f, 10.f / (sqrtf(tot) + 1e-6f));
    }
    __syncthreads();
    float coef = coefS;
    int stride = gridDim.x * 256;
    for (int e = blockIdx.x * 256 + t; e < total; e += stride) {
        unsigned m = (unsigned)e / 193u;
        unsigned i = (unsigned)e - m * 193u;
        out[(size_t)m * OSTR + NPAR + i] *= coef;
    }
}

extern "C" void kernel_launch(void* const* d_in, const int* in_sizes, int n_in,
                              void* d_out, int out_size, void* d_ws, size_t ws_size,
                              hipStream_t stream) {
    const float* W1 = (const float*)d_in[0];
    const float* b1 = (const float*)d_in[1];
    const float* W2 = (const float*)d_in[2];
    const float* b2 = (const float*)d_in[3];
    const float* W3 = (const float*)d_in[4];
    const float* b3 = (const float*)d_in[5];
    const float* G1 = (const float*)d_in[6];
    const float* G2 = (const float*)d_in[7];
    const float* G3 = (const float*)d_in[8];
    const float* G4 = (const float*)d_in[9];
    const float* G5 = (const float*)d_in[10];
    const float* G6 = (const float*)d_in[11];
    const float* dx = (const float*)d_in[12];
    const float* fv = (const float*)d_in[13];
    const int*   dy = (const int*)d_in[14];
    const int*   st = (const int*)d_in[15];
    float* out   = (float*)d_out;
    float* slots = (float*)d_ws;

    int Bn = in_sizes[0] / 40;
    int storeMode = (ws_size >= (size_t)(Bn + 2) * sizeof(float)) ? 1 : 0;

    if (!storeMode) hipMemsetAsync(d_ws, 0, 4100, stream);   // atomic path only
    int nb = (Bn + 1) / 2;
    mlp_kernelA<<<nb, 192, 0, stream>>>(W1,b1,W2,b2,W3,b3,
                                        G1,G2,G3,G4,G5,G6,
                                        dx,fv,dy,st,out,slots,Bn,storeMode);
    int total = Bn * NPAR;
    mlp_kernelBC<<<1024, 256, 0, stream>>>(out, slots,
                                           storeMode ? Bn : 1024, total);
}

// Round 8
// 289.263 us; speedup vs baseline: 1.4175x; 1.4175x over previous
//
#include <hip/hip_runtime.h>
#include <hip/hip_bf16.h>

#define NPTS 150
#define KP   168          // padded K for MFMA; 5 K-steps of 32 cover 0..159
#define NPAR 193
#define OSTR 388

// bf16 transposed activation buffers, element offsets into sT
#define H1T  0            // [11][168]  rows 0..9 = h1^T, row 10 = ones (db2)
#define H2T  1848         // [11][168]  rows 0..9 = h2^T, row 10 = ones (db3)
#define XT   3696         // [5][168]   rows 0..3 = x^T,  row 4  = ones (db1)
#define DZ2T 4536         // [10][168]
#define DZ1T 6216         // [10][168]
#define DLT  7896         // [3][168]
#define TTOT 8400         // 50 rows x 168

typedef __attribute__((ext_vector_type(8))) short short8;
typedef __attribute__((ext_vector_type(4))) float f32x4;
typedef __attribute__((ext_vector_type(2))) float f32x2;

__constant__ float LRS[6] = {0.001f, 0.01f, 0.05f, 0.1f, 0.5f, 1.0f};

// EMPIRICAL LAW (rounds 1-7): VGPR=84 kernels run at occ ~31.6% (177-190us);
// VGPR>=88 kernels collapse to occ ~17% (270-340us) REGARDLESS of the change
// (r4: +4 VGPR, near-identical body -> occupancy halved). Keep the r1
// skeleton exactly: 1 MLP/block, 192 thr, interleaved stores, 3 barriers.
// Round-8 diet (VGPR-neutral): (a) pad-only LDS zero (cols 150-159 x 50 rows,
// 2 aligned stores/row vs 1050 f32x4) — data cols 0..149 of all 50 rows are
// fully written before B2; MFMA never reads cols>=160; A-side pads zeroed so
// pad products are 0 regardless of B pad values. (b) ones-fill t<150 only.
// (c) w2/w3/bb preload via aligned ds_read_b64 (64 reads vs 126).
__global__ __launch_bounds__(192)
__attribute__((amdgpu_waves_per_eu(2, 4)))
void mlp_kernelA(
    const float* __restrict__ W1, const float* __restrict__ b1,
    const float* __restrict__ W2, const float* __restrict__ b2,
    const float* __restrict__ W3, const float* __restrict__ b3,
    const float* __restrict__ G1, const float* __restrict__ G2,
    const float* __restrict__ G3, const float* __restrict__ G4,
    const float* __restrict__ G5, const float* __restrict__ G6,
    const float* __restrict__ dx, const float* __restrict__ fv,
    const int* __restrict__ dy, const int* __restrict__ stepsz,
    float* __restrict__ out, float* __restrict__ slots, int storeMode)
{
    const int m    = blockIdx.x;
    const int t    = threadIdx.x;
    const int lane = t & 63;
    const int w    = t >> 6;

    __shared__ alignas(16) __hip_bfloat16 sT[TTOT];
    __shared__ alignas(16) float sP[200];
    __shared__ float red[8];

    const float lr = LRS[stepsz[m]];

    // ---- SGD update: each thread computes param index t (t=0 also does 192) ----
    float pv;
    if      (t < 40)  pv = W1[m*40 + t]        - lr * G1[m*40 + t];
    else if (t < 50)  pv = b1[m*10 + (t-40)]   - lr * G2[m*10 + (t-40)];
    else if (t < 150) pv = W2[m*100 + (t-50)]  - lr * G3[m*100 + (t-50)];
    else if (t < 160) pv = b2[m*10 + (t-150)]  - lr * G4[m*10 + (t-150)];
    else if (t < 190) pv = W3[m*30 + (t-160)]  - lr * G5[m*30 + (t-160)];
    else              pv = b3[m*3 + (t-190)]   - lr * G6[m*3 + (t-190)];
    sP[t] = pv;
    out[(size_t)m*OSTR + t] = fminf(fmaxf(pv, -10000.f), 10000.f);
    if (t == 0) {
        float p192 = b3[m*3 + 2] - lr * G6[m*3 + 2];
        sP[192] = p192;
        out[(size_t)m*OSTR + 192] = fminf(fmaxf(p192, -10000.f), 10000.f);
    }

    // ---- pad-only zero: cols 150..159 of all 50 rows (MFMA k-range is
    //      0..159; cols 160..167 are never read; cols 0..149 fully written
    //      below). Aligned: row base byte = 336r (16|336), +304 for col 152,
    //      +300 for col 150. ----
    if (t < 100) {
        int r = t >> 1;
        __hip_bfloat16* rowp = sT + r*KP;
        if (t & 1) {
            *(float*)(rowp + 150) = 0.f;          // cols 150,151
        } else {
            f32x4 z = {0.f, 0.f, 0.f, 0.f};
            *(f32x4*)(rowp + 152) = z;            // cols 152..159
        }
    }
    // ---- ones rows, data cols only ----
    if (t < NPTS) {
        __hip_bfloat16 one = __float2bfloat16(1.0f);
        sT[H1T + 10*KP + t] = one;
        sT[H2T + 10*KP + t] = one;
        sT[XT  +  4*KP + t] = one;
    }
    // ---- x^T fill: x^T[f][n] = x[n][f] ----
    for (int i = t; i < 600; i += 192) {
        int n = i >> 2, f = i & 3;
        sT[XT + f*KP + n] = __float2bfloat16(dx[i]);
    }

    __syncthreads();   // B1: sP + sT staging complete

    // ---- per-wave preload via aligned f32x2 LDS reads (all offsets even) ----
    float w2[10][10], bb2[10], w3[3][10], bb3[3], bb1[10];
    {
        const f32x2* p2 = (const f32x2*)sP;
        #pragma unroll
        for (int g = 0; g < 10; g++) {
            #pragma unroll
            for (int p = 0; p < 5; p++) {
                f32x2 v = p2[(50 + g*10)/2 + p];
                w2[g][2*p] = v.x; w2[g][2*p+1] = v.y;
            }
        }
        #pragma unroll
        for (int p = 0; p < 5; p++) {
            f32x2 v = p2[75 + p];                 // sP[150..159]
            bb2[2*p] = v.x; bb2[2*p+1] = v.y;
        }
        #pragma unroll
        for (int o = 0; o < 3; o++) {
            #pragma unroll
            for (int p = 0; p < 5; p++) {
                f32x2 v = p2[(160 + o*10)/2 + p];
                w3[o][2*p] = v.x; w3[o][2*p+1] = v.y;
            }
        }
        {
            f32x2 v = p2[95];                     // sP[190],sP[191]
            bb3[0] = v.x; bb3[1] = v.y; bb3[2] = sP[192];
        }
        #pragma unroll
        for (int p = 0; p < 5; p++) {
            f32x2 v = p2[20 + p];                 // sP[40..49]
            bb1[2*p] = v.x; bb1[2*p+1] = v.y;
        }
    }
    const f32x4* sP4 = (const f32x4*)sP;   // W1 row j at sP4[j]

    // ================= fused forward + backward-dz: ONE point per thread =====
    float lossacc = 0.f, ssacc = 0.f;
    {
        const int  n   = t;
        const bool act = (n < NPTS);
        const int  nc  = act ? n : 0;

        f32x4 xv = ((const f32x4*)dx)[nc];
        int   yv = dy[nc];

        float h1v[10];
        #pragma unroll
        for (int j = 0; j < 10; j++) {
            f32x4 wv = sP4[j];
            float z = bb1[j] + xv.x*wv.x + xv.y*wv.y + xv.z*wv.z + xv.w*wv.w;
            h1v[j] = fmaxf(z, 0.f);
        }
        float h2v[10];
        #pragma unroll
        for (int g = 0; g < 10; g++) {
            float z = bb2[g];
            #pragma unroll
            for (int h = 0; h < 10; h++) z += h1v[h] * w2[g][h];
            h2v[g] = fmaxf(z, 0.f);
        }
        float lg[3];
        #pragma unroll
        for (int o = 0; o < 3; o++) {
            float z = bb3[o];
            #pragma unroll
            for (int g = 0; g < 10; g++) z += h2v[g] * w3[o][g];
            lg[o] = z;
        }
        float mx = fmaxf(lg[0], fmaxf(lg[1], lg[2]));
        float e0 = __expf(lg[0]-mx), e1 = __expf(lg[1]-mx), e2 = __expf(lg[2]-mx);
        float s   = e0 + e1 + e2;
        float inv = 1.f / s;
        float lse = mx + __logf(s);
        float ly  = (yv == 0) ? lg[0] : ((yv == 1) ? lg[1] : lg[2]);
        lossacc = act ? (lse - ly) : 0.f;

        float dl[3];
        dl[0] = (e0*inv - ((yv==0)?1.f:0.f)) * (1.f/150.f);
        dl[1] = (e1*inv - ((yv==1)?1.f:0.f)) * (1.f/150.f);
        dl[2] = (e2*inv - ((yv==2)?1.f:0.f)) * (1.f/150.f);

        float dz2v[10];
        #pragma unroll
        for (int g = 0; g < 10; g++) {
            float d = dl[0]*w3[0][g] + dl[1]*w3[1][g] + dl[2]*w3[2][g];
            dz2v[g] = (h2v[g] > 0.f) ? d : 0.f;
        }
        float dz1v[10];
        #pragma unroll
        for (int h = 0; h < 10; h++) {
            float d = 0.f;
            #pragma unroll
            for (int g = 0; g < 10; g++) d += dz2v[g] * w2[g][h];
            dz1v[h] = (h1v[h] > 0.f) ? d : 0.f;
        }

        if (act) {
            #pragma unroll
            for (int j = 0; j < 10; j++) sT[H1T  + j*KP + n] = __float2bfloat16(h1v[j]);
            #pragma unroll
            for (int g = 0; g < 10; g++) sT[H2T  + g*KP + n] = __float2bfloat16(h2v[g]);
            #pragma unroll
            for (int o = 0; o < 3;  o++) sT[DLT  + o*KP + n] = __float2bfloat16(dl[o]);
            #pragma unroll
            for (int g = 0; g < 10; g++) sT[DZ2T + g*KP + n] = __float2bfloat16(dz2v[g]);
            #pragma unroll
            for (int h = 0; h < 10; h++) sT[DZ1T + h*KP + n] = __float2bfloat16(dz1v[h]);
        }
    }
    __syncthreads();   // B2

    // ================= weight-grad GEMMs via MFMA: one tile per wave =========
    {
        const short* sTs = reinterpret_cast<const short*>(sT);
        const int mrow = lane & 15, q = lane >> 4;

        int abase, arows, bbase, bcols, woff, nW, boff;
        if      (w == 0) { abase=DZ2T; arows=10; bbase=H1T; bcols=11; woff=50;  nW=10; boff=150; }
        else if (w == 1) { abase=DZ1T; arows=10; bbase=XT;  bcols=5;  woff=0;   nW=4;  boff=40;  }
        else             { abase=DLT;  arows=3;  bbase=H2T; bcols=11; woff=160; nW=10; boff=190; }

        int ar = (mrow < arows) ? mrow : 0;
        int br = (mrow < bcols) ? mrow : 0;
        f32x4 acc = {0.f, 0.f, 0.f, 0.f};
        #pragma unroll
        for (int kk = 0; kk < 5; kk++) {
            int k0 = kk*32 + q*8;
            short8 a = *(const short8*)(sTs + abase + ar*KP + k0);
            short8 b = *(const short8*)(sTs + bbase + br*KP + k0);
            acc = __builtin_amdgcn_mfma_f32_16x16x32_bf16(a, b, acc, 0, 0, 0);
        }
        #pragma unroll
        for (int r = 0; r < 4; r++) {
            int row = q*4 + r;
            if (row < arows && mrow < bcols) {
                float v = acc[r];
                int off = (mrow < nW) ? (woff + row*nW + mrow) : (boff + row);
                out[(size_t)m*OSTR + NPAR + off] = v;   // raw grad; kernel C scales
                ssacc += v*v;
            }
        }
    }

    // ---- reductions: loss (across all 3 waves), sumsq (per-wave tiles) ----
    #pragma unroll
    for (int off = 32; off > 0; off >>= 1) {
        lossacc += __shfl_down(lossacc, off, 64);
        ssacc   += __shfl_down(ssacc,   off, 64);
    }
    if (lane == 0) { red[w] = lossacc; red[4 + w] = ssacc; }
    __syncthreads();   // B3
    if (t == 0) {
        float blockss = red[4] + red[5] + red[6];
        if (storeMode) slots[1 + m] = blockss;
        else           atomicAdd(&slots[1 + (m & 1023)], blockss);
        float loss = (red[0] + red[1] + red[2]) * (1.f/150.f);
        out[(size_t)m*OSTR + 386] = loss;
        float imp = fv[m] - loss;
        imp = fminf(fmaxf(imp, -10000.f), 10000.f);
        out[(size_t)m*OSTR + 387] = imp;
    }
}

// 64-block reduction of slots[1..1+count) -> raw total into slots[0] (r3's
// best-measured non-A shape).
__global__ __launch_bounds__(256) void mlp_kernelB(float* __restrict__ slots, int count)
{
    int idx = blockIdx.x * 256 + threadIdx.x;
    int stride = gridDim.x * 256;
    float v = 0.f;
    for (int i = idx; i < count; i += stride) v += slots[1 + i];
    #pragma unroll
    for (int off = 32; off > 0; off >>= 1) v += __shfl_down(v, off, 64);
    __shared__ float red[4];
    int t = threadIdx.x;
    if ((t & 63) == 0) red[t >> 6] = v;
    __syncthreads();
    if (t == 0) {
        float total = red[0] + red[1] + red[2] + red[3];
        atomicAdd(&slots[0], total);
    }
}

// One block per MLP, coalesced RMW over the 193 grad slots; coef derived
// in-register from the raw total.
__global__ __launch_bounds__(192) void mlp_kernelC(float* __restrict__ out,
                                                   const float* __restrict__ slots)
{
    float total = slots[0];
    float coef = fminf(1.f, 10.f / (sqrtf(total) + 1e-6f));
    size_t base = (size_t)blockIdx.x * OSTR + NPAR;
    int t = threadIdx.x;
    out[base + t] *= coef;
    if (t == 0) out[base + 192] *= coef;
}

extern "C" void kernel_launch(void* const* d_in, const int* in_sizes, int n_in,
                              void* d_out, int out_size, void* d_ws, size_t ws_size,
                              hipStream_t stream) {
    const float* W1 = (const float*)d_in[0];
    const float* b1 = (const float*)d_in[1];
    const float* W2 = (const float*)d_in[2];
    const float* b2 = (const float*)d_in[3];
    const float* W3 = (const float*)d_in[4];
    const float* b3 = (const float*)d_in[5];
    const float* G1 = (const float*)d_in[6];
    const float* G2 = (const float*)d_in[7];
    const float* G3 = (const float*)d_in[8];
    const float* G4 = (const float*)d_in[9];
    const float* G5 = (const float*)d_in[10];
    const float* G6 = (const float*)d_in[11];
    const float* dx = (const float*)d_in[12];
    const float* fv = (const float*)d_in[13];
    const int*   dy = (const int*)d_in[14];
    const int*   st = (const int*)d_in[15];
    float* out   = (float*)d_out;
    float* slots = (float*)d_ws;

    int Bn = in_sizes[0] / 40;
    int storeMode = (ws_size >= (size_t)(Bn + 2) * sizeof(float)) ? 1 : 0;

    if (storeMode) hipMemsetAsync(d_ws, 0, 4, stream);       // just slots[0]
    else           hipMemsetAsync(d_ws, 0, 4100, stream);    // slots[0..1024]
    mlp_kernelA<<<Bn, 192, 0, stream>>>(W1,b1,W2,b2,W3,b3,
                                        G1,G2,G3,G4,G5,G6,
                                        dx,fv,dy,st,out,slots,storeMode);
    mlp_kernelB<<<64, 256, 0, stream>>>(slots, storeMode ? Bn : 1024);
    mlp_kernelC<<<Bn, 192, 0, stream>>>(out, slots);
}

// Round 9
// 262.949 us; speedup vs baseline: 1.5593x; 1.1001x over previous
//
#include <hip/hip_runtime.h>
#include <hip/hip_bf16.h>

#define NPTS 150
#define KP   168          // padded K for MFMA; 5 K-steps of 32 cover 0..159
#define NPAR 193
#define OSTR 388

// bf16 transposed activation buffers, element offsets into sT
#define H1T  0            // [11][168]  rows 0..9 = h1^T, row 10 = ones (db2)
#define H2T  1848         // [11][168]  rows 0..9 = h2^T, row 10 = ones (db3)
#define XT   3696         // [5][168]   rows 0..3 = x^T,  row 4  = ones (db1)
#define DZ2T 4536         // [10][168]
#define DZ1T 6216         // [10][168]
#define DLT  7896         // [3][168]
#define TTOT 8400         // 50 rows x 168

typedef __attribute__((ext_vector_type(8))) short short8;
typedef __attribute__((ext_vector_type(4))) float f32x4;
typedef __attribute__((ext_vector_type(2))) float f32x2;

__constant__ float LRS[6] = {0.001f, 0.01f, 0.05f, 0.1f, 0.5f, 1.0f};

// EMPIRICAL LAWS (rounds 1-8):
//  - VGPR=84 <-> occ 31.6% (177-190us); VGPR>=88 <-> occ ~17% (270-340us),
//    for EVERY structural variant tried. Keep the r1 skeleton untouched.
//  - VALU instr count is not binding (r3); barrier drains not binding (r4);
//    fewer/bigger blocks fail via the VGPR cliff (r2/r5/r7).
//  - Critical-path instruction diet at constant VGPR pays ~1us / 3 instr
//    (r8: pad-only zero + f32x2 preload -> 183->177).
// Round-9 diet: x^T fill from the already-loaded xv registers (kills the
// 600-elem strided loop + redundant dx stream); everything else = r8.
__global__ __launch_bounds__(192)
__attribute__((amdgpu_waves_per_eu(2, 4)))
void mlp_kernelA(
    const float* __restrict__ W1, const float* __restrict__ b1,
    const float* __restrict__ W2, const float* __restrict__ b2,
    const float* __restrict__ W3, const float* __restrict__ b3,
    const float* __restrict__ G1, const float* __restrict__ G2,
    const float* __restrict__ G3, const float* __restrict__ G4,
    const float* __restrict__ G5, const float* __restrict__ G6,
    const float* __restrict__ dx, const float* __restrict__ fv,
    const int* __restrict__ dy, const int* __restrict__ stepsz,
    float* __restrict__ out, float* __restrict__ slots, int storeMode)
{
    const int m    = blockIdx.x;
    const int t    = threadIdx.x;
    const int lane = t & 63;
    const int w    = t >> 6;

    __shared__ alignas(16) __hip_bfloat16 sT[TTOT];
    __shared__ alignas(16) float sP[200];
    __shared__ float red[8];

    const float lr = LRS[stepsz[m]];

    // ---- SGD update: each thread computes param index t (t=0 also does 192) ----
    float pv;
    if      (t < 40)  pv = W1[m*40 + t]        - lr * G1[m*40 + t];
    else if (t < 50)  pv = b1[m*10 + (t-40)]   - lr * G2[m*10 + (t-40)];
    else if (t < 150) pv = W2[m*100 + (t-50)]  - lr * G3[m*100 + (t-50)];
    else if (t < 160) pv = b2[m*10 + (t-150)]  - lr * G4[m*10 + (t-150)];
    else if (t < 190) pv = W3[m*30 + (t-160)]  - lr * G5[m*30 + (t-160)];
    else              pv = b3[m*3 + (t-190)]   - lr * G6[m*3 + (t-190)];
    sP[t] = pv;
    out[(size_t)m*OSTR + t] = fminf(fmaxf(pv, -10000.f), 10000.f);
    if (t == 0) {
        float p192 = b3[m*3 + 2] - lr * G6[m*3 + 2];
        sP[192] = p192;
        out[(size_t)m*OSTR + 192] = fminf(fmaxf(p192, -10000.f), 10000.f);
    }

    // ---- per-thread data point (early: HBM latency overlaps staging) ----
    const bool act = (t < NPTS);
    const int  nc  = act ? t : 0;
    const f32x4 xv = ((const f32x4*)dx)[nc];
    const int   yv = dy[nc];

    // ---- pad-only zero: cols 150..159 of all 50 rows (MFMA k-range is
    //      0..159; cols 160..167 never read; cols 0..149 fully written). ----
    if (t < 100) {
        int r = t >> 1;
        __hip_bfloat16* rowp = sT + r*KP;
        if (t & 1) {
            *(float*)(rowp + 150) = 0.f;          // cols 150,151
        } else {
            f32x4 z = {0.f, 0.f, 0.f, 0.f};
            *(f32x4*)(rowp + 152) = z;            // cols 152..159
        }
    }
    // ---- ones rows (data cols) + x^T from registers: x^T[f][t] = xv[f] ----
    if (act) {
        __hip_bfloat16 one = __float2bfloat16(1.0f);
        sT[H1T + 10*KP + t] = one;
        sT[H2T + 10*KP + t] = one;
        sT[XT  +  4*KP + t] = one;
        sT[XT  +  0*KP + t] = __float2bfloat16(xv.x);
        sT[XT  +  1*KP + t] = __float2bfloat16(xv.y);
        sT[XT  +  2*KP + t] = __float2bfloat16(xv.z);
        sT[XT  +  3*KP + t] = __float2bfloat16(xv.w);
    }

    __syncthreads();   // B1: sP + sT staging complete

    // ---- per-wave preload via aligned f32x2 LDS reads (all offsets even) ----
    float w2[10][10], bb2[10], w3[3][10], bb3[3], bb1[10];
    {
        const f32x2* p2 = (const f32x2*)sP;
        #pragma unroll
        for (int g = 0; g < 10; g++) {
            #pragma unroll
            for (int p = 0; p < 5; p++) {
                f32x2 v = p2[(50 + g*10)/2 + p];
                w2[g][2*p] = v.x; w2[g][2*p+1] = v.y;
            }
        }
        #pragma unroll
        for (int p = 0; p < 5; p++) {
            f32x2 v = p2[75 + p];                 // sP[150..159]
            bb2[2*p] = v.x; bb2[2*p+1] = v.y;
        }
        #pragma unroll
        for (int o = 0; o < 3; o++) {
            #pragma unroll
            for (int p = 0; p < 5; p++) {
                f32x2 v = p2[(160 + o*10)/2 + p];
                w3[o][2*p] = v.x; w3[o][2*p+1] = v.y;
            }
        }
        {
            f32x2 v = p2[95];                     // sP[190],sP[191]
            bb3[0] = v.x; bb3[1] = v.y; bb3[2] = sP[192];
        }
        #pragma unroll
        for (int p = 0; p < 5; p++) {
            f32x2 v = p2[20 + p];                 // sP[40..49]
            bb1[2*p] = v.x; bb1[2*p+1] = v.y;
        }
    }
    const f32x4* sP4 = (const f32x4*)sP;   // W1 row j at sP4[j]

    // ================= fused forward + backward-dz: ONE point per thread =====
    float lossacc = 0.f, ssacc = 0.f;
    {
        const int n = t;

        float h1v[10];
        #pragma unroll
        for (int j = 0; j < 10; j++) {
            f32x4 wv = sP4[j];
            float z = bb1[j] + xv.x*wv.x + xv.y*wv.y + xv.z*wv.z + xv.w*wv.w;
            h1v[j] = fmaxf(z, 0.f);
        }
        float h2v[10];
        #pragma unroll
        for (int g = 0; g < 10; g++) {
            float z = bb2[g];
            #pragma unroll
            for (int h = 0; h < 10; h++) z += h1v[h] * w2[g][h];
            h2v[g] = fmaxf(z, 0.f);
        }
        float lg[3];
        #pragma unroll
        for (int o = 0; o < 3; o++) {
            float z = bb3[o];
            #pragma unroll
            for (int g = 0; g < 10; g++) z += h2v[g] * w3[o][g];
            lg[o] = z;
        }
        float mx = fmaxf(lg[0], fmaxf(lg[1], lg[2]));
        float e0 = __expf(lg[0]-mx), e1 = __expf(lg[1]-mx), e2 = __expf(lg[2]-mx);
        float s   = e0 + e1 + e2;
        float inv = 1.f / s;
        float lse = mx + __logf(s);
        float ly  = (yv == 0) ? lg[0] : ((yv == 1) ? lg[1] : lg[2]);
        lossacc = act ? (lse - ly) : 0.f;

        float dl[3];
        dl[0] = (e0*inv - ((yv==0)?1.f:0.f)) * (1.f/150.f);
        dl[1] = (e1*inv - ((yv==1)?1.f:0.f)) * (1.f/150.f);
        dl[2] = (e2*inv - ((yv==2)?1.f:0.f)) * (1.f/150.f);

        float dz2v[10];
        #pragma unroll
        for (int g = 0; g < 10; g++) {
            float d = dl[0]*w3[0][g] + dl[1]*w3[1][g] + dl[2]*w3[2][g];
            dz2v[g] = (h2v[g] > 0.f) ? d : 0.f;
        }
        float dz1v[10];
        #pragma unroll
        for (int h = 0; h < 10; h++) {
            float d = 0.f;
            #pragma unroll
            for (int g = 0; g < 10; g++) d += dz2v[g] * w2[g][h];
            dz1v[h] = (h1v[h] > 0.f) ? d : 0.f;
        }

        if (act) {
            #pragma unroll
            for (int j = 0; j < 10; j++) sT[H1T  + j*KP + n] = __float2bfloat16(h1v[j]);
            #pragma unroll
            for (int g = 0; g < 10; g++) sT[H2T  + g*KP + n] = __float2bfloat16(h2v[g]);
            #pragma unroll
            for (int o = 0; o < 3;  o++) sT[DLT  + o*KP + n] = __float2bfloat16(dl[o]);
            #pragma unroll
            for (int g = 0; g < 10; g++) sT[DZ2T + g*KP + n] = __float2bfloat16(dz2v[g]);
            #pragma unroll
            for (int h = 0; h < 10; h++) sT[DZ1T + h*KP + n] = __float2bfloat16(dz1v[h]);
        }
    }
    __syncthreads();   // B2

    // ================= weight-grad GEMMs via MFMA: one tile per wave =========
    {
        const short* sTs = reinterpret_cast<const short*>(sT);
        const int mrow = lane & 15, q = lane >> 4;

        int abase, arows, bbase, bcols, woff, nW, boff;
        if      (w == 0) { abase=DZ2T; arows=10; bbase=H1T; bcols=11; woff=50;  nW=10; boff=150; }
        else if (w == 1) { abase=DZ1T; arows=10; bbase=XT;  bcols=5;  woff=0;   nW=4;  boff=40;  }
        else             { abase=DLT;  arows=3;  bbase=H2T; bcols=11; woff=160; nW=10; boff=190; }

        int ar = (mrow < arows) ? mrow : 0;
        int br = (mrow < bcols) ? mrow : 0;
        f32x4 acc = {0.f, 0.f, 0.f, 0.f};
        #pragma unroll
        for (int kk = 0; kk < 5; kk++) {
            int k0 = kk*32 + q*8;
            short8 a = *(const short8*)(sTs + abase + ar*KP + k0);
            short8 b = *(const short8*)(sTs + bbase + br*KP + k0);
            acc = __builtin_amdgcn_mfma_f32_16x16x32_bf16(a, b, acc, 0, 0, 0);
        }
        #pragma unroll
        for (int r = 0; r < 4; r++) {
            int row = q*4 + r;
            if (row < arows && mrow < bcols) {
                float v = acc[r];
                int off = (mrow < nW) ? (woff + row*nW + mrow) : (boff + row);
                out[(size_t)m*OSTR + NPAR + off] = v;   // raw grad; kernel C scales
                ssacc += v*v;
            }
        }
    }

    // ---- reductions: loss (across all 3 waves), sumsq (per-wave tiles) ----
    #pragma unroll
    for (int off = 32; off > 0; off >>= 1) {
        lossacc += __shfl_down(lossacc, off, 64);
        ssacc   += __shfl_down(ssacc,   off, 64);
    }
    if (lane == 0) { red[w] = lossacc; red[4 + w] = ssacc; }
    __syncthreads();   // B3
    if (t == 0) {
        float blockss = red[4] + red[5] + red[6];
        if (storeMode) slots[1 + m] = blockss;
        else           atomicAdd(&slots[1 + (m & 1023)], blockss);
        float loss = (red[0] + red[1] + red[2]) * (1.f/150.f);
        out[(size_t)m*OSTR + 386] = loss;
        float imp = fv[m] - loss;
        imp = fminf(fmaxf(imp, -10000.f), 10000.f);
        out[(size_t)m*OSTR + 387] = imp;
    }
}

// 64-block reduction -> raw total into slots[0]. slots[0] is memset to 0 in
// both modes, so summing slots[0..count] INCLUSIVE == slots[1..count] and
// lets us use aligned f32x4 loads from the base.
__global__ __launch_bounds__(256) void mlp_kernelB(float* __restrict__ slots, int count)
{
    int idx = blockIdx.x * 256 + threadIdx.x;
    int stride = gridDim.x * 256;
    int n4 = (count + 1) >> 2;                  // f32x4 chunks covering 0..4*n4-1
    const f32x4* s4 = (const f32x4*)slots;
    float v = 0.f;
    for (int i = idx; i < n4; i += stride) {
        f32x4 q = s4[i];
        v += q.x + q.y + q.z + q.w;
    }
    if (idx == 0)                                // tail elements 4*n4 .. count
        for (int i = 4*n4; i <= count; i++) v += slots[i];
    #pragma unroll
    for (int off = 32; off > 0; off >>= 1) v += __shfl_down(v, off, 64);
    __shared__ float red[4];
    int t = threadIdx.x;
    if ((t & 63) == 0) red[t >> 6] = v;
    __syncthreads();
    if (t == 0) {
        float total = red[0] + red[1] + red[2] + red[3];
        atomicAdd(&slots[0], total);
    }
}

// One block per MLP, coalesced RMW over the 193 grad slots; coef derived
// in-register from the raw total.
__global__ __launch_bounds__(192) void mlp_kernelC(float* __restrict__ out,
                                                   const float* __restrict__ slots)
{
    float total = slots[0];
    float coef = fminf(1.f, 10.f / (sqrtf(total) + 1e-6f));
    size_t base = (size_t)blockIdx.x * OSTR + NPAR;
    int t = threadIdx.x;
    out[base + t] *= coef;
    if (t == 0) out[base + 192] *= coef;
}

extern "C" void kernel_launch(void* const* d_in, const int* in_sizes, int n_in,
                              void* d_out, int out_size, void* d_ws, size_t ws_size,
                              hipStream_t stream) {
    const float* W1 = (const float*)d_in[0];
    const float* b1 = (const float*)d_in[1];
    const float* W2 = (const float*)d_in[2];
    const float* b2 = (const float*)d_in[3];
    const float* W3 = (const float*)d_in[4];
    const float* b3 = (const float*)d_in[5];
    const float* G1 = (const float*)d_in[6];
    const float* G2 = (const float*)d_in[7];
    const float* G3 = (const float*)d_in[8];
    const float* G4 = (const float*)d_in[9];
    const float* G5 = (const float*)d_in[10];
    const float* G6 = (const float*)d_in[11];
    const float* dx = (const float*)d_in[12];
    const float* fv = (const float*)d_in[13];
    const int*   dy = (const int*)d_in[14];
    const int*   st = (const int*)d_in[15];
    float* out   = (float*)d_out;
    float* slots = (float*)d_ws;

    int Bn = in_sizes[0] / 40;
    int storeMode = (ws_size >= (size_t)(Bn + 2) * sizeof(float)) ? 1 : 0;

    if (storeMode) hipMemsetAsync(d_ws, 0, 4, stream);       // just slots[0]
    else           hipMemsetAsync(d_ws, 0, 4100, stream);    // slots[0..1024]
    mlp_kernelA<<<Bn, 192, 0, stream>>>(W1,b1,W2,b2,W3,b3,
                                        G1,G2,G3,G4,G5,G6,
                                        dx,fv,dy,st,out,slots,storeMode);
    mlp_kernelB<<<64, 256, 0, stream>>>(slots, storeMode ? Bn : 1024);
    mlp_kernelC<<<Bn, 192, 0, stream>>>(out, slots);
}